// Round 15
// baseline (129.219 us; speedup 1.0000x reference)
//
#include <hip/hip_runtime.h>

#define NN 16
#define KK 256
#define TT 1000
#define MM 384
#define TCH 8      // t's per k_score block (125 blocks exactly, no tail)
#define TOB 28     // t's per k_out block (fallback path)
#define TP 1008    // padded T stride for fallback fp32 E_T
#define TPAD 1024  // padded T rows for bf16 ET (MFMA path)

typedef short bf16x8 __attribute__((ext_vector_type(8)));
typedef float f32x4 __attribute__((ext_vector_type(4)));

__device__ __forceinline__ float fast_rcp(float x) { return __builtin_amdgcn_rcpf(x); }
__device__ __forceinline__ float silu_f(float x) {
    float e = __expf(-x);
    return x * fast_rcp(1.0f + e);
}
__device__ __forceinline__ unsigned short f2bf_rne(float f) {
    unsigned u = __float_as_uint(f);
    unsigned r = u + 0x7fff + ((u >> 16) & 1);
    return (unsigned short)(r >> 16);
}
__device__ __forceinline__ float bf2f(unsigned short h) {
    return __uint_as_float((unsigned)h << 16);
}

// ---- K1 fat: scan (16 blocks) + V^T bf16 (nvt blocks) + conv (1024 blocks) ----
// conv computes d=relu(exp(dur)-1) locally -> no dependency on scan output.
// (R12-proven version: 36 KB LDS, direct 3-tap global V reads.)
__global__ __launch_bounds__(256) void k_init(
    const float* __restrict__ dur_out, float* __restrict__ wsS,
    const float* __restrict__ V,
    unsigned short* __restrict__ Vth, unsigned short* __restrict__ Vtl,
    const float* __restrict__ conv_w, const float* __restrict__ conv_b,
    const float* __restrict__ bn_g, const float* __restrict__ bn_b,
    const float* __restrict__ bn_m, const float* __restrict__ bn_v,
    const float* __restrict__ w1, const float* __restrict__ b1,
    const float* __restrict__ aw1, const float* __restrict__ ab1,
    float* __restrict__ wsQ1, float* __restrict__ wsQA, int nvt) {
    __shared__ float shmem[8 * 3 * MM];   // 36 KB union: scan(1KB)/tile(16.3KB)/wt
    int tid = threadIdx.x;
    int bid = blockIdx.x;

    if (bid < 16) {
        // ---- scan ----
        float* lds = shmem;
        int n = bid, k = tid;
        float d = __expf(dur_out[n * KK + k]) - 1.0f;
        d = fmaxf(d, 0.0f);
        lds[k] = d;
        __syncthreads();
        float run = d;
        for (int off = 1; off < KK; off <<= 1) {
            float v = (k >= off) ? lds[k - off] : 0.0f;
            __syncthreads();
            run += v;
            lds[k] = run;
            __syncthreads();
        }
        wsS[n * KK + k] = run - d;
    } else if (bid < 16 + nvt) {
        // ---- V -> V^T bf16 hi/lo ----
        float (*tile)[65] = (float(*)[65])shmem;
        int id = bid - 16;
        int m0 = (id % 6) * 64;
        int k0 = ((id / 6) & 3) * 64;
        int n = id / 24;
        const float* Vn = V + (size_t)n * KK * MM;
        int mo = tid & 63, ks = tid >> 6;
        for (int kk = ks; kk < 64; kk += 4)
            tile[kk][mo] = Vn[(size_t)(k0 + kk) * MM + m0 + mo];
        __syncthreads();
        int ko = tid & 63, ms = tid >> 6;
        for (int mm = ms; mm < 64; mm += 4) {
            float v = tile[ko][mm];
            unsigned short hi = f2bf_rne(v);
            unsigned short lo = f2bf_rne(v - bf2f(hi));
            size_t o = ((size_t)n * MM + m0 + mm) * KK + k0 + ko;
            Vth[o] = hi;
            Vtl[o] = lo;
        }
    } else {
        // ---- conv1d(3,same)+BN+silu -> fold into q1/qA ----
        float* wt = shmem;   // [c][tap][m]
        int id = bid - 16 - nvt;
        int kcb = id & 63;
        int n = id >> 6;
        for (int i = tid; i < 3 * MM * 8; i += 256) {
            int tap = i / (MM * 8);
            int r = i - tap * (MM * 8);
            int m = r >> 3, c = r & 7;
            wt[(c * 3 + tap) * MM + m] = conv_w[i];
        }
        __syncthreads();

        int wv = tid >> 6, lane = tid & 63;
        int k = kcb * 4 + wv;
        const float* Vn = V + (size_t)n * KK * MM;

        float p[8];
#pragma unroll
        for (int c = 0; c < 8; ++c) p[c] = 0.f;

#pragma unroll
        for (int tap = 0; tap < 3; ++tap) {
            int kk = k + tap - 1;
            if (kk < 0 || kk >= KK) continue;   // wave-uniform branch
            const float* vrow = Vn + (size_t)kk * MM;
#pragma unroll
            for (int j = 0; j < 6; ++j) {
                int m = lane + 64 * j;
                float v = vrow[m];              // coalesced
#pragma unroll
                for (int c = 0; c < 8; ++c)
                    p[c] = fmaf(v, wt[(c * 3 + tap) * MM + m], p[c]);
            }
        }
#pragma unroll
        for (int c = 0; c < 8; ++c) {
#pragma unroll
            for (int off = 32; off >= 1; off >>= 1) p[c] += __shfl_xor(p[c], off);
        }
        float cv[8];
#pragma unroll
        for (int c = 0; c < 8; ++c) {
            float xx = p[c] + conv_b[c];
            float bn = (xx - bn_m[c]) * (bn_g[c] * rsqrtf(bn_v[c] + 1e-3f)) + bn_b[c];
            cv[c] = silu_f(bn);
        }
        float d = fmaxf(__expf(dur_out[n * KK + k]) - 1.0f, 0.0f);  // local, no dep
        if (lane < 16) {
            int j = lane;
            float q = fmaf(d, w1[16 + j], b1[j]);
#pragma unroll
            for (int c = 0; c < 8; ++c) q = fmaf(cv[c], w1[(2 + c) * 16 + j], q);
            wsQ1[((size_t)(n * KK + k)) * 16 + j] = q;
        } else if (lane < 18) {
            int pp = lane - 16;
            float q = fmaf(d, aw1[2 + pp], ab1[pp]);
#pragma unroll
            for (int c = 0; c < 8; ++c) q = fmaf(cv[c], aw1[(2 + c) * 2 + pp], q);
            wsQA[(size_t)(n * KK + k) * 2 + pp] = q;
        }
    }
}

// ---------------- K3a: scores -> softmax -> E (bf16 split or fp32) + aux C ----
// Phase A: t-quad with exp-chaining (exp(-(u+r)) = exp(-u)*exp(-r)); w2/w3 via
// uniform scalar loads. NO min-waves launch bound (caps spill -- R3/R4 lesson).
__global__ __launch_bounds__(256) void k_score(
    const float* __restrict__ w1, const float* __restrict__ w2g,
    const float* __restrict__ b2g, const float* __restrict__ w3g,
    const float* __restrict__ b3g, const float* __restrict__ aw1,
    const float* __restrict__ aw2g, const float* __restrict__ ab2g,
    const float* __restrict__ wsS, const float* __restrict__ wsQ1,
    const float* __restrict__ wsQA, float* __restrict__ wcg,
    float* __restrict__ ETf, unsigned short* __restrict__ ETh,
    unsigned short* __restrict__ ETl, int use_bf16) {
    __shared__ __align__(16) float sc[TCH * KK];   // 8 KB
    __shared__ __align__(16) float rl[16];

    int tid = threadIdx.x;
    int tb = blockIdx.x * TCH;
    int n = blockIdx.y;
    int nK = n * KK;

    if (tid < 16) rl[tid] = w1[tid] - w1[16 + tid];

    float b3v = b3g[0];
    float b2r[16];
    {
        const float4* bp = (const float4*)b2g;
#pragma unroll
        for (int g = 0; g < 4; ++g) {
            float4 b = bp[g];
            b2r[4 * g + 0] = b.x; b2r[4 * g + 1] = b.y;
            b2r[4 * g + 2] = b.z; b2r[4 * g + 3] = b.w;
        }
    }
    int k = tid;
    float S_k = wsS[nK + k];
    float q1[16];
    {
        const float4* q1p = (const float4*)&wsQ1[(size_t)(nK + k) * 16];
#pragma unroll
        for (int g = 0; g < 4; ++g) {
            float4 qv = q1p[g];
            q1[4 * g + 0] = qv.x; q1[4 * g + 1] = qv.y;
            q1[4 * g + 2] = qv.z; q1[4 * g + 3] = qv.w;
        }
    }
    __syncthreads();

    float er[16];
#pragma unroll
    for (int j = 0; j < 16; ++j) er[j] = __expf(-rl[j]);

    // ---- phase A: scores, 4 t's at a time; acc pre-seeded with b2 ----
    for (int tq = 0; tq < TCH / 4; ++tq) {
        float s0 = (float)(tb + 4 * tq + 1) - S_k;
        float aA[16], aB[16], aC[16], aD[16];
#pragma unroll
        for (int j = 0; j < 16; ++j) {
            aA[j] = b2r[j]; aB[j] = b2r[j]; aC[j] = b2r[j]; aD[j] = b2r[j];
        }
#pragma unroll
        for (int j1 = 0; j1 < 16; ++j1) {
            float r = rl[j1];
            float q = q1[j1];
            float uA = fmaf(s0, r, q);
            float uB = uA + r;
            float uC = uB + r;
            float uD = uC + r;
            float ej = er[j1];
            float eA = __expf(-uA);
            float eB = eA * ej;
            float eC = eB * ej;
            float eD = eC * ej;
            float hA = uA * fast_rcp(1.0f + eA);
            float hB = uB * fast_rcp(1.0f + eB);
            float hC = uC * fast_rcp(1.0f + eC);
            float hD = uD * fast_rcp(1.0f + eD);
            const float4* wr = (const float4*)&w2g[j1 * 16];   // uniform -> s_load
#pragma unroll
            for (int g = 0; g < 4; ++g) {
                float4 w = wr[g];
                aA[4 * g + 0] = fmaf(hA, w.x, aA[4 * g + 0]);
                aA[4 * g + 1] = fmaf(hA, w.y, aA[4 * g + 1]);
                aA[4 * g + 2] = fmaf(hA, w.z, aA[4 * g + 2]);
                aA[4 * g + 3] = fmaf(hA, w.w, aA[4 * g + 3]);
                aB[4 * g + 0] = fmaf(hB, w.x, aB[4 * g + 0]);
                aB[4 * g + 1] = fmaf(hB, w.y, aB[4 * g + 1]);
                aB[4 * g + 2] = fmaf(hB, w.z, aB[4 * g + 2]);
                aB[4 * g + 3] = fmaf(hB, w.w, aB[4 * g + 3]);
                aC[4 * g + 0] = fmaf(hC, w.x, aC[4 * g + 0]);
                aC[4 * g + 1] = fmaf(hC, w.y, aC[4 * g + 1]);
                aC[4 * g + 2] = fmaf(hC, w.z, aC[4 * g + 2]);
                aC[4 * g + 3] = fmaf(hC, w.w, aC[4 * g + 3]);
                aD[4 * g + 0] = fmaf(hD, w.x, aD[4 * g + 0]);
                aD[4 * g + 1] = fmaf(hD, w.y, aD[4 * g + 1]);
                aD[4 * g + 2] = fmaf(hD, w.z, aD[4 * g + 2]);
                aD[4 * g + 3] = fmaf(hD, w.w, aD[4 * g + 3]);
            }
        }
        float scA = b3v, scB = b3v, scC = b3v, scD = b3v;
#pragma unroll
        for (int g = 0; g < 4; ++g) {
            float4 wq = *(const float4*)&w3g[4 * g];   // uniform -> s_load
            scA = fmaf(silu_f(aA[4 * g + 0]), wq.x, scA);
            scA = fmaf(silu_f(aA[4 * g + 1]), wq.y, scA);
            scA = fmaf(silu_f(aA[4 * g + 2]), wq.z, scA);
            scA = fmaf(silu_f(aA[4 * g + 3]), wq.w, scA);
            scB = fmaf(silu_f(aB[4 * g + 0]), wq.x, scB);
            scB = fmaf(silu_f(aB[4 * g + 1]), wq.y, scB);
            scB = fmaf(silu_f(aB[4 * g + 2]), wq.z, scB);
            scB = fmaf(silu_f(aB[4 * g + 3]), wq.w, scB);
            scC = fmaf(silu_f(aC[4 * g + 0]), wq.x, scC);
            scC = fmaf(silu_f(aC[4 * g + 1]), wq.y, scC);
            scC = fmaf(silu_f(aC[4 * g + 2]), wq.z, scC);
            scC = fmaf(silu_f(aC[4 * g + 3]), wq.w, scC);
            scD = fmaf(silu_f(aD[4 * g + 0]), wq.x, scD);
            scD = fmaf(silu_f(aD[4 * g + 1]), wq.y, scD);
            scD = fmaf(silu_f(aD[4 * g + 2]), wq.z, scD);
            scD = fmaf(silu_f(aD[4 * g + 3]), wq.w, scD);
        }
        sc[(4 * tq + 0) * KK + k] = scA;
        sc[(4 * tq + 1) * KK + k] = scB;
        sc[(4 * tq + 2) * KK + k] = scC;
        sc[(4 * tq + 3) * KK + k] = scD;
    }
    __syncthreads();

    // ---- softmax over k (wave-parallel) + aux C; normalize in place ----
    {
        float rA0 = aw1[0] - aw1[2];
        float rA1 = aw1[1] - aw1[3];
        float aw200 = aw2g[0], aw201 = aw2g[1], aw210 = aw2g[2], aw211 = aw2g[3];
        float ab20 = ab2g[0], ab21 = ab2g[1];
        int wv = tid >> 6, lane = tid & 63;
        float S4[4]; float2 QA4[4];
#pragma unroll
        for (int j = 0; j < 4; ++j) {
            int kk2 = lane + 64 * j;
            S4[j] = wsS[nK + kk2];
            QA4[j] = *(const float2*)&wsQA[(size_t)(nK + kk2) * 2];
        }
#pragma unroll
        for (int i = 0; i < 2; ++i) {
            int t = wv * 2 + i;
            int tt = tb + t;
            float v0 = sc[t * KK + lane];
            float v1 = sc[t * KK + lane + 64];
            float v2 = sc[t * KK + lane + 128];
            float v3 = sc[t * KK + lane + 192];
            float mx = fmaxf(fmaxf(v0, v1), fmaxf(v2, v3));
#pragma unroll
            for (int off = 32; off >= 1; off >>= 1) mx = fmaxf(mx, __shfl_xor(mx, off));
            float e0 = __expf(v0 - mx), e1 = __expf(v1 - mx);
            float e2 = __expf(v2 - mx), e3 = __expf(v3 - mx);
            float ssum = e0 + e1 + e2 + e3;
            float wc0 = 0.f, wc1 = 0.f;
            float tc = (float)(tt + 1);
            float ear[4] = {e0, e1, e2, e3};
#pragma unroll
            for (int j = 0; j < 4; ++j) {
                float s = tc - S4[j];
                float a0 = silu_f(fmaf(s, rA0, QA4[j].x));
                float a1 = silu_f(fmaf(s, rA1, QA4[j].y));
                float c0 = silu_f(fmaf(a1, aw210, fmaf(a0, aw200, ab20)));
                float c1 = silu_f(fmaf(a1, aw211, fmaf(a0, aw201, ab21)));
                wc0 = fmaf(ear[j], c0, wc0);
                wc1 = fmaf(ear[j], c1, wc1);
            }
#pragma unroll
            for (int off = 32; off >= 1; off >>= 1) {
                ssum += __shfl_xor(ssum, off);
                wc0 += __shfl_xor(wc0, off);
                wc1 += __shfl_xor(wc1, off);
            }
            float inv = fast_rcp(ssum);
            sc[t * KK + lane]       = e0 * inv;
            sc[t * KK + lane + 64]  = e1 * inv;
            sc[t * KK + lane + 128] = e2 * inv;
            sc[t * KK + lane + 192] = e3 * inv;
            if (lane == 0) {
                wcg[(size_t)(n * TT + tt) * 2]     = wc0 * inv;
                wcg[(size_t)(n * TT + tt) * 2 + 1] = wc1 * inv;
            }
        }
    }
    __syncthreads();

    if (use_bf16) {
#pragma unroll
        for (int t2 = 0; t2 < TCH; ++t2) {
            float e = sc[t2 * KK + k];
            unsigned short hi = f2bf_rne(e);
            unsigned short lo = f2bf_rne(e - bf2f(hi));
            size_t o = ((size_t)n * TPAD + tb + t2) * KK + k;
            ETh[o] = hi;
            ETl[o] = lo;
        }
    } else {
        for (int idx = tid; idx < TCH * KK; idx += 256) {
            int k2 = idx >> 3, t2 = idx & 7;
            ETf[((size_t)(nK + k2)) * TP + tb + t2] = sc[t2 * KK + k2];
        }
    }
}

// ---------------- K3b (MFMA): O = E @ V + aux, 64t per block -----------------
// 768 thr = 12 waves = 2 t-subtiles(32t) x 6 m-tiles(64m); per-wave code is the
// R9-proven 32t x 64m shape (acc[2][4], 2 MFMA per V load). Grid (16,16) = 256
// blocks -> V read 16x/n instead of 32x (halves L2 V traffic), 12 waves/CU.
// 3-term compensated bf16: EhVh + EhVl + ElVh, fp32 accumulate.
__global__ __launch_bounds__(768) void k_gemm(
    const unsigned short* __restrict__ ETh, const unsigned short* __restrict__ ETl,
    const unsigned short* __restrict__ Vth, const unsigned short* __restrict__ Vtl,
    const float* __restrict__ wcg, const float* __restrict__ projw,
    float* __restrict__ out) {
    int tid = threadIdx.x;
    int w = tid >> 6, lane = tid & 63;
    int ts = (w >= 6) ? 1 : 0;          // t-subtile within block
    int wm = (w >= 6) ? (w - 6) : w;    // m-tile index 0..5
    int tb = blockIdx.x * 64 + ts * 32;
    int n = blockIdx.y;
    int r16 = lane & 15, kh = lane >> 4;
    int mb = wm * 64;

    const unsigned short* eh0 = ETh + ((size_t)n * TPAD + tb + r16) * KK + kh * 8;
    const unsigned short* el0 = ETl + ((size_t)n * TPAD + tb + r16) * KK + kh * 8;
    const unsigned short* vh0 = Vth + ((size_t)n * MM + mb + r16) * KK + kh * 8;
    const unsigned short* vl0 = Vtl + ((size_t)n * MM + mb + r16) * KK + kh * 8;

    f32x4 acc[2][4];
#pragma unroll
    for (int tt = 0; tt < 2; ++tt)
#pragma unroll
        for (int mm = 0; mm < 4; ++mm) acc[tt][mm] = (f32x4){0.f, 0.f, 0.f, 0.f};

#pragma unroll
    for (int kb = 0; kb < 8; ++kb) {
        int ko = kb * 32;
        bf16x8 ah0 = *(const bf16x8*)(eh0 + ko);
        bf16x8 ah1 = *(const bf16x8*)(eh0 + 16 * KK + ko);
        bf16x8 al0 = *(const bf16x8*)(el0 + ko);
        bf16x8 al1 = *(const bf16x8*)(el0 + 16 * KK + ko);
#pragma unroll
        for (int mm = 0; mm < 4; ++mm) {
            bf16x8 bh = *(const bf16x8*)(vh0 + (size_t)mm * 16 * KK + ko);
            bf16x8 bl = *(const bf16x8*)(vl0 + (size_t)mm * 16 * KK + ko);
            acc[0][mm] = __builtin_amdgcn_mfma_f32_16x16x32_bf16(ah0, bh, acc[0][mm], 0, 0, 0);
            acc[0][mm] = __builtin_amdgcn_mfma_f32_16x16x32_bf16(ah0, bl, acc[0][mm], 0, 0, 0);
            acc[0][mm] = __builtin_amdgcn_mfma_f32_16x16x32_bf16(al0, bh, acc[0][mm], 0, 0, 0);
            acc[1][mm] = __builtin_amdgcn_mfma_f32_16x16x32_bf16(ah1, bh, acc[1][mm], 0, 0, 0);
            acc[1][mm] = __builtin_amdgcn_mfma_f32_16x16x32_bf16(ah1, bl, acc[1][mm], 0, 0, 0);
            acc[1][mm] = __builtin_amdgcn_mfma_f32_16x16x32_bf16(al1, bh, acc[1][mm], 0, 0, 0);
        }
    }

#pragma unroll
    for (int tt = 0; tt < 2; ++tt) {
#pragma unroll
        for (int r = 0; r < 4; ++r) {
            int t = tb + tt * 16 + kh * 4 + r;
            if (t < TT) {
                float c0 = wcg[(size_t)(n * TT + t) * 2];
                float c1 = wcg[(size_t)(n * TT + t) * 2 + 1];
#pragma unroll
                for (int mm = 0; mm < 4; ++mm) {
                    int m = mb + mm * 16 + r16;
                    float pw0 = projw[m], pw1 = projw[MM + m];
                    out[((size_t)n * TT + t) * MM + m] =
                        acc[tt][mm][r] + c0 * pw0 + c1 * pw1;
                }
            }
        }
    }
}

// ---------------- K3b (fallback): s_load E rows + coalesced V (R7) -----------
__global__ __launch_bounds__(384) void k_out(
    const float* __restrict__ V, const float* __restrict__ projw,
    const float* __restrict__ wcg, const float* __restrict__ ET,
    float* __restrict__ out) {
    int tid = threadIdx.x;
    int tb = blockIdx.x * TOB;
    int n = blockIdx.y;
    int nK = n * KK;
    const float* Vn = V + (size_t)n * KK * MM;
    const float* Eb = ET + (size_t)nK * TP + tb;
    int m = tid;

    float acc[TOB];
#pragma unroll
    for (int t = 0; t < TOB; ++t) acc[t] = 0.f;

    for (int kx = 0; kx < KK; ++kx) {
        const float4* ep = (const float4*)(Eb + (size_t)kx * TP);  // uniform -> s_load
        float vv = Vn[(size_t)kx * MM + m];
#pragma unroll
        for (int q = 0; q < TOB / 4; ++q) {
            float4 e = ep[q];
            acc[4 * q + 0] = fmaf(e.x, vv, acc[4 * q + 0]);
            acc[4 * q + 1] = fmaf(e.y, vv, acc[4 * q + 1]);
            acc[4 * q + 2] = fmaf(e.z, vv, acc[4 * q + 2]);
            acc[4 * q + 3] = fmaf(e.w, vv, acc[4 * q + 3]);
        }
    }

    float pw0 = projw[m], pw1 = projw[MM + m];
#pragma unroll
    for (int t = 0; t < TOB; ++t) {
        int tt = tb + t;
        if (tt < TT) {
            float c0 = wcg[(size_t)(n * TT + tt) * 2];
            float c1 = wcg[(size_t)(n * TT + tt) * 2 + 1];
            out[((size_t)n * TT + tt) * MM + m] = acc[t] + c0 * pw0 + c1 * pw1;
        }
    }
}

extern "C" void kernel_launch(void* const* d_in, const int* in_sizes, int n_in,
                              void* d_out, int out_size, void* d_ws, size_t ws_size,
                              hipStream_t stream) {
    const float* V   = (const float*)d_in[0];
    const float* dur = (const float*)d_in[1];
    const float* cw  = (const float*)d_in[2];
    const float* cb  = (const float*)d_in[3];
    const float* bng = (const float*)d_in[4];
    const float* bnb = (const float*)d_in[5];
    const float* bnm = (const float*)d_in[6];
    const float* bnv = (const float*)d_in[7];
    const float* w1  = (const float*)d_in[8];
    const float* b1  = (const float*)d_in[9];
    const float* w2  = (const float*)d_in[10];
    const float* b2  = (const float*)d_in[11];
    const float* w3  = (const float*)d_in[12];
    const float* b3  = (const float*)d_in[13];
    const float* aw1 = (const float*)d_in[14];
    const float* ab1 = (const float*)d_in[15];
    const float* aw2 = (const float*)d_in[16];
    const float* ab2 = (const float*)d_in[17];
    const float* pw  = (const float*)d_in[18];
    float* out = (float*)d_out;
    float* ws = (float*)d_ws;

    float* wsS  = ws;                 // 4096 floats
    float* wsQ1 = ws + 8192;          // 65536
    float* wsQA = ws + 73728;         // 8192
    float* wcg  = ws + 81920;         // 32768
    char*  base = (char*)(ws + 114688);

    size_t sz_ETh = (size_t)NN * TPAD * KK * 2;   // 8,388,608
    size_t sz_Vt  = (size_t)NN * MM * KK * 2;     // 3,145,728
    size_t need   = 114688 * 4 + 2 * sz_ETh + 2 * sz_Vt;   // ~23.5 MB
    bool mfma_path = (ws_size >= need);

    if (mfma_path) {
        unsigned short* ETh = (unsigned short*)base;
        unsigned short* ETl = (unsigned short*)(base + sz_ETh);
        unsigned short* Vth = (unsigned short*)(base + 2 * sz_ETh);
        unsigned short* Vtl = (unsigned short*)(base + 2 * sz_ETh + sz_Vt);
        int nvt = 6 * 4 * NN;   // 384
        hipLaunchKernelGGL(k_init, dim3(16 + nvt + 64 * NN), dim3(256), 0, stream,
                           dur, wsS, V, Vth, Vtl, cw, cb, bng, bnb, bnm, bnv,
                           w1, b1, aw1, ab1, wsQ1, wsQA, nvt);
        hipLaunchKernelGGL(k_score, dim3(TT / TCH, NN), dim3(256), 0,
                           stream, w1, w2, b2, w3, b3, aw1, aw2, ab2, wsS, wsQ1,
                           wsQA, wcg, (float*)nullptr, ETh, ETl, 1);
        hipLaunchKernelGGL(k_gemm, dim3(TPAD / 64, NN), dim3(768), 0, stream,
                           ETh, ETl, Vth, Vtl, wcg, pw, out);
    } else {
        float* ETf = (float*)base;
        hipLaunchKernelGGL(k_init, dim3(16 + 64 * NN), dim3(256), 0, stream,
                           dur, wsS, V, (unsigned short*)nullptr,
                           (unsigned short*)nullptr, cw, cb, bng, bnb, bnm, bnv,
                           w1, b1, aw1, ab1, wsQ1, wsQA, 0);
        hipLaunchKernelGGL(k_score, dim3(TT / TCH, NN), dim3(256), 0,
                           stream, w1, w2, b2, w3, b3, aw1, aw2, ab2, wsS, wsQ1,
                           wsQA, wcg, ETf, (unsigned short*)nullptr,
                           (unsigned short*)nullptr, 0);
        hipLaunchKernelGGL(k_out, dim3((TT + TOB - 1) / TOB, NN), dim3(384), 0,
                           stream, V, pw, wcg, ETf, out);
    }
}

// Round 16
// 123.418 us; speedup vs baseline: 1.0470x; 1.0470x over previous
//
#include <hip/hip_runtime.h>

#define NN 16
#define KK 256
#define TT 1000
#define MM 384
#define TCH 8      // t's per k_score block (125 blocks exactly, no tail)
#define TOB 28     // t's per k_out block (fallback path)
#define TP 1008    // padded T stride for fallback fp32 E_T
#define TPAD 1024  // padded T rows for bf16 ET (MFMA path)

typedef short bf16x8 __attribute__((ext_vector_type(8)));
typedef float f32x4 __attribute__((ext_vector_type(4)));

__device__ __forceinline__ float fast_rcp(float x) { return __builtin_amdgcn_rcpf(x); }
__device__ __forceinline__ float silu_f(float x) {
    float e = __expf(-x);
    return x * fast_rcp(1.0f + e);
}
__device__ __forceinline__ unsigned short f2bf_rne(float f) {
    unsigned u = __float_as_uint(f);
    unsigned r = u + 0x7fff + ((u >> 16) & 1);
    return (unsigned short)(r >> 16);
}
__device__ __forceinline__ float bf2f(unsigned short h) {
    return __uint_as_float((unsigned)h << 16);
}

// ---- K1 fat: scan (16 blocks) + V^T bf16 (nvt blocks) + conv (1024 blocks) ----
// conv computes d=relu(exp(dur)-1) locally -> no dependency on scan output.
__global__ __launch_bounds__(256) void k_init(
    const float* __restrict__ dur_out, float* __restrict__ wsS,
    const float* __restrict__ V,
    unsigned short* __restrict__ Vth, unsigned short* __restrict__ Vtl,
    const float* __restrict__ conv_w, const float* __restrict__ conv_b,
    const float* __restrict__ bn_g, const float* __restrict__ bn_b,
    const float* __restrict__ bn_m, const float* __restrict__ bn_v,
    const float* __restrict__ w1, const float* __restrict__ b1,
    const float* __restrict__ aw1, const float* __restrict__ ab1,
    float* __restrict__ wsQ1, float* __restrict__ wsQA, int nvt) {
    __shared__ float shmem[8 * 3 * MM];   // 36 KB union: scan(1KB)/tile(16.3KB)/wt
    int tid = threadIdx.x;
    int bid = blockIdx.x;

    if (bid < 16) {
        // ---- scan ----
        float* lds = shmem;
        int n = bid, k = tid;
        float d = __expf(dur_out[n * KK + k]) - 1.0f;
        d = fmaxf(d, 0.0f);
        lds[k] = d;
        __syncthreads();
        float run = d;
        for (int off = 1; off < KK; off <<= 1) {
            float v = (k >= off) ? lds[k - off] : 0.0f;
            __syncthreads();
            run += v;
            lds[k] = run;
            __syncthreads();
        }
        wsS[n * KK + k] = run - d;
    } else if (bid < 16 + nvt) {
        // ---- V -> V^T bf16 hi/lo ----
        float (*tile)[65] = (float(*)[65])shmem;
        int id = bid - 16;
        int m0 = (id % 6) * 64;
        int k0 = ((id / 6) & 3) * 64;
        int n = id / 24;
        const float* Vn = V + (size_t)n * KK * MM;
        int mo = tid & 63, ks = tid >> 6;
        for (int kk = ks; kk < 64; kk += 4)
            tile[kk][mo] = Vn[(size_t)(k0 + kk) * MM + m0 + mo];
        __syncthreads();
        int ko = tid & 63, ms = tid >> 6;
        for (int mm = ms; mm < 64; mm += 4) {
            float v = tile[ko][mm];
            unsigned short hi = f2bf_rne(v);
            unsigned short lo = f2bf_rne(v - bf2f(hi));
            size_t o = ((size_t)n * MM + m0 + mm) * KK + k0 + ko;
            Vth[o] = hi;
            Vtl[o] = lo;
        }
    } else {
        // ---- conv1d(3,same)+BN+silu -> fold into q1/qA ----
        float* wt = shmem;   // [c][tap][m]
        int id = bid - 16 - nvt;
        int kcb = id & 63;
        int n = id >> 6;
        for (int i = tid; i < 3 * MM * 8; i += 256) {
            int tap = i / (MM * 8);
            int r = i - tap * (MM * 8);
            int m = r >> 3, c = r & 7;
            wt[(c * 3 + tap) * MM + m] = conv_w[i];
        }
        __syncthreads();

        int wv = tid >> 6, lane = tid & 63;
        int k = kcb * 4 + wv;
        const float* Vn = V + (size_t)n * KK * MM;

        float p[8];
#pragma unroll
        for (int c = 0; c < 8; ++c) p[c] = 0.f;

#pragma unroll
        for (int tap = 0; tap < 3; ++tap) {
            int kk = k + tap - 1;
            if (kk < 0 || kk >= KK) continue;   // wave-uniform branch
            const float* vrow = Vn + (size_t)kk * MM;
#pragma unroll
            for (int j = 0; j < 6; ++j) {
                int m = lane + 64 * j;
                float v = vrow[m];              // coalesced
#pragma unroll
                for (int c = 0; c < 8; ++c)
                    p[c] = fmaf(v, wt[(c * 3 + tap) * MM + m], p[c]);
            }
        }
#pragma unroll
        for (int c = 0; c < 8; ++c) {
#pragma unroll
            for (int off = 32; off >= 1; off >>= 1) p[c] += __shfl_xor(p[c], off);
        }
        float cv[8];
#pragma unroll
        for (int c = 0; c < 8; ++c) {
            float xx = p[c] + conv_b[c];
            float bn = (xx - bn_m[c]) * (bn_g[c] * rsqrtf(bn_v[c] + 1e-3f)) + bn_b[c];
            cv[c] = silu_f(bn);
        }
        float d = fmaxf(__expf(dur_out[n * KK + k]) - 1.0f, 0.0f);  // local, no dep
        if (lane < 16) {
            int j = lane;
            float q = fmaf(d, w1[16 + j], b1[j]);
#pragma unroll
            for (int c = 0; c < 8; ++c) q = fmaf(cv[c], w1[(2 + c) * 16 + j], q);
            wsQ1[((size_t)(n * KK + k)) * 16 + j] = q;
        } else if (lane < 18) {
            int pp = lane - 16;
            float q = fmaf(d, aw1[2 + pp], ab1[pp]);
#pragma unroll
            for (int c = 0; c < 8; ++c) q = fmaf(cv[c], aw1[(2 + c) * 2 + pp], q);
            wsQA[(size_t)(n * KK + k) * 2 + pp] = q;
        }
    }
}

// ---------------- K3a: scores -> softmax -> E (bf16 or fp32) + aux C ---------
// Phase A: t-quad with exp-chaining; w2/w3 via uniform scalar loads.
// NO min-waves launch bound (caps spill -- R3/R4 lesson).
__global__ __launch_bounds__(256) void k_score(
    const float* __restrict__ w1, const float* __restrict__ w2g,
    const float* __restrict__ b2g, const float* __restrict__ w3g,
    const float* __restrict__ b3g, const float* __restrict__ aw1,
    const float* __restrict__ aw2g, const float* __restrict__ ab2g,
    const float* __restrict__ wsS, const float* __restrict__ wsQ1,
    const float* __restrict__ wsQA, float* __restrict__ wcg,
    float* __restrict__ ETf, unsigned short* __restrict__ ETh,
    int use_bf16) {
    __shared__ __align__(16) float sc[TCH * KK];   // 8 KB
    __shared__ __align__(16) float rl[16];

    int tid = threadIdx.x;
    int tb = blockIdx.x * TCH;
    int n = blockIdx.y;
    int nK = n * KK;

    if (tid < 16) rl[tid] = w1[tid] - w1[16 + tid];

    float b3v = b3g[0];
    float b2r[16];
    {
        const float4* bp = (const float4*)b2g;
#pragma unroll
        for (int g = 0; g < 4; ++g) {
            float4 b = bp[g];
            b2r[4 * g + 0] = b.x; b2r[4 * g + 1] = b.y;
            b2r[4 * g + 2] = b.z; b2r[4 * g + 3] = b.w;
        }
    }
    int k = tid;
    float S_k = wsS[nK + k];
    float q1[16];
    {
        const float4* q1p = (const float4*)&wsQ1[(size_t)(nK + k) * 16];
#pragma unroll
        for (int g = 0; g < 4; ++g) {
            float4 qv = q1p[g];
            q1[4 * g + 0] = qv.x; q1[4 * g + 1] = qv.y;
            q1[4 * g + 2] = qv.z; q1[4 * g + 3] = qv.w;
        }
    }
    __syncthreads();

    float er[16];
#pragma unroll
    for (int j = 0; j < 16; ++j) er[j] = __expf(-rl[j]);

    // ---- phase A: scores, 4 t's at a time; acc pre-seeded with b2 ----
    for (int tq = 0; tq < TCH / 4; ++tq) {
        float s0 = (float)(tb + 4 * tq + 1) - S_k;
        float aA[16], aB[16], aC[16], aD[16];
#pragma unroll
        for (int j = 0; j < 16; ++j) {
            aA[j] = b2r[j]; aB[j] = b2r[j]; aC[j] = b2r[j]; aD[j] = b2r[j];
        }
#pragma unroll
        for (int j1 = 0; j1 < 16; ++j1) {
            float r = rl[j1];
            float q = q1[j1];
            float uA = fmaf(s0, r, q);
            float uB = uA + r;
            float uC = uB + r;
            float uD = uC + r;
            float ej = er[j1];
            float eA = __expf(-uA);
            float eB = eA * ej;
            float eC = eB * ej;
            float eD = eC * ej;
            float hA = uA * fast_rcp(1.0f + eA);
            float hB = uB * fast_rcp(1.0f + eB);
            float hC = uC * fast_rcp(1.0f + eC);
            float hD = uD * fast_rcp(1.0f + eD);
            const float4* wr = (const float4*)&w2g[j1 * 16];   // uniform -> s_load
#pragma unroll
            for (int g = 0; g < 4; ++g) {
                float4 w = wr[g];
                aA[4 * g + 0] = fmaf(hA, w.x, aA[4 * g + 0]);
                aA[4 * g + 1] = fmaf(hA, w.y, aA[4 * g + 1]);
                aA[4 * g + 2] = fmaf(hA, w.z, aA[4 * g + 2]);
                aA[4 * g + 3] = fmaf(hA, w.w, aA[4 * g + 3]);
                aB[4 * g + 0] = fmaf(hB, w.x, aB[4 * g + 0]);
                aB[4 * g + 1] = fmaf(hB, w.y, aB[4 * g + 1]);
                aB[4 * g + 2] = fmaf(hB, w.z, aB[4 * g + 2]);
                aB[4 * g + 3] = fmaf(hB, w.w, aB[4 * g + 3]);
                aC[4 * g + 0] = fmaf(hC, w.x, aC[4 * g + 0]);
                aC[4 * g + 1] = fmaf(hC, w.y, aC[4 * g + 1]);
                aC[4 * g + 2] = fmaf(hC, w.z, aC[4 * g + 2]);
                aC[4 * g + 3] = fmaf(hC, w.w, aC[4 * g + 3]);
                aD[4 * g + 0] = fmaf(hD, w.x, aD[4 * g + 0]);
                aD[4 * g + 1] = fmaf(hD, w.y, aD[4 * g + 1]);
                aD[4 * g + 2] = fmaf(hD, w.z, aD[4 * g + 2]);
                aD[4 * g + 3] = fmaf(hD, w.w, aD[4 * g + 3]);
            }
        }
        float scA = b3v, scB = b3v, scC = b3v, scD = b3v;
#pragma unroll
        for (int g = 0; g < 4; ++g) {
            float4 wq = *(const float4*)&w3g[4 * g];   // uniform -> s_load
            scA = fmaf(silu_f(aA[4 * g + 0]), wq.x, scA);
            scA = fmaf(silu_f(aA[4 * g + 1]), wq.y, scA);
            scA = fmaf(silu_f(aA[4 * g + 2]), wq.z, scA);
            scA = fmaf(silu_f(aA[4 * g + 3]), wq.w, scA);
            scB = fmaf(silu_f(aB[4 * g + 0]), wq.x, scB);
            scB = fmaf(silu_f(aB[4 * g + 1]), wq.y, scB);
            scB = fmaf(silu_f(aB[4 * g + 2]), wq.z, scB);
            scB = fmaf(silu_f(aB[4 * g + 3]), wq.w, scB);
            scC = fmaf(silu_f(aC[4 * g + 0]), wq.x, scC);
            scC = fmaf(silu_f(aC[4 * g + 1]), wq.y, scC);
            scC = fmaf(silu_f(aC[4 * g + 2]), wq.z, scC);
            scC = fmaf(silu_f(aC[4 * g + 3]), wq.w, scC);
            scD = fmaf(silu_f(aD[4 * g + 0]), wq.x, scD);
            scD = fmaf(silu_f(aD[4 * g + 1]), wq.y, scD);
            scD = fmaf(silu_f(aD[4 * g + 2]), wq.z, scD);
            scD = fmaf(silu_f(aD[4 * g + 3]), wq.w, scD);
        }
        sc[(4 * tq + 0) * KK + k] = scA;
        sc[(4 * tq + 1) * KK + k] = scB;
        sc[(4 * tq + 2) * KK + k] = scC;
        sc[(4 * tq + 3) * KK + k] = scD;
    }
    __syncthreads();

    // ---- softmax over k (wave-parallel) + aux C; normalize in place ----
    {
        float rA0 = aw1[0] - aw1[2];
        float rA1 = aw1[1] - aw1[3];
        float aw200 = aw2g[0], aw201 = aw2g[1], aw210 = aw2g[2], aw211 = aw2g[3];
        float ab20 = ab2g[0], ab21 = ab2g[1];
        int wv = tid >> 6, lane = tid & 63;
        float S4[4]; float2 QA4[4];
#pragma unroll
        for (int j = 0; j < 4; ++j) {
            int kk2 = lane + 64 * j;
            S4[j] = wsS[nK + kk2];
            QA4[j] = *(const float2*)&wsQA[(size_t)(nK + kk2) * 2];
        }
#pragma unroll
        for (int i = 0; i < 2; ++i) {
            int t = wv * 2 + i;
            int tt = tb + t;
            float v0 = sc[t * KK + lane];
            float v1 = sc[t * KK + lane + 64];
            float v2 = sc[t * KK + lane + 128];
            float v3 = sc[t * KK + lane + 192];
            float mx = fmaxf(fmaxf(v0, v1), fmaxf(v2, v3));
#pragma unroll
            for (int off = 32; off >= 1; off >>= 1) mx = fmaxf(mx, __shfl_xor(mx, off));
            float e0 = __expf(v0 - mx), e1 = __expf(v1 - mx);
            float e2 = __expf(v2 - mx), e3 = __expf(v3 - mx);
            float ssum = e0 + e1 + e2 + e3;
            float wc0 = 0.f, wc1 = 0.f;
            float tc = (float)(tt + 1);
            float ear[4] = {e0, e1, e2, e3};
#pragma unroll
            for (int j = 0; j < 4; ++j) {
                float s = tc - S4[j];
                float a0 = silu_f(fmaf(s, rA0, QA4[j].x));
                float a1 = silu_f(fmaf(s, rA1, QA4[j].y));
                float c0 = silu_f(fmaf(a1, aw210, fmaf(a0, aw200, ab20)));
                float c1 = silu_f(fmaf(a1, aw211, fmaf(a0, aw201, ab21)));
                wc0 = fmaf(ear[j], c0, wc0);
                wc1 = fmaf(ear[j], c1, wc1);
            }
#pragma unroll
            for (int off = 32; off >= 1; off >>= 1) {
                ssum += __shfl_xor(ssum, off);
                wc0 += __shfl_xor(wc0, off);
                wc1 += __shfl_xor(wc1, off);
            }
            float inv = fast_rcp(ssum);
            sc[t * KK + lane]       = e0 * inv;
            sc[t * KK + lane + 64]  = e1 * inv;
            sc[t * KK + lane + 128] = e2 * inv;
            sc[t * KK + lane + 192] = e3 * inv;
            if (lane == 0) {
                wcg[(size_t)(n * TT + tt) * 2]     = wc0 * inv;
                wcg[(size_t)(n * TT + tt) * 2 + 1] = wc1 * inv;
            }
        }
    }
    __syncthreads();

    if (use_bf16) {
        // E as bf16 hi only (E in [0,1], normalized; El term dropped -- error
        // ~1e-3 vs 1.89e-2 threshold; V keeps hi/lo split in k_gemm)
#pragma unroll
        for (int t2 = 0; t2 < TCH; ++t2) {
            float e = sc[t2 * KK + k];
            size_t o = ((size_t)n * TPAD + tb + t2) * KK + k;
            ETh[o] = f2bf_rne(e);
        }
    } else {
        for (int idx = tid; idx < TCH * KK; idx += 256) {
            int k2 = idx >> 3, t2 = idx & 7;
            ETf[((size_t)(nK + k2)) * TP + tb + t2] = sc[t2 * KK + k2];
        }
    }
}

// ---------------- K3b (MFMA): O = E @ V + aux, 64t per block, 2-term ---------
// 768 thr = 12 waves = 2 t-subtiles(32t) x 6 m-tiles(64m). Per (kb,mm,tt):
// EhVh + EhVl (El term dropped -- see k_score). fp32 accumulate.
__global__ __launch_bounds__(768) void k_gemm(
    const unsigned short* __restrict__ ETh,
    const unsigned short* __restrict__ Vth, const unsigned short* __restrict__ Vtl,
    const float* __restrict__ wcg, const float* __restrict__ projw,
    float* __restrict__ out) {
    int tid = threadIdx.x;
    int w = tid >> 6, lane = tid & 63;
    int ts = (w >= 6) ? 1 : 0;          // t-subtile within block
    int wm = (w >= 6) ? (w - 6) : w;    // m-tile index 0..5
    int tb = blockIdx.x * 64 + ts * 32;
    int n = blockIdx.y;
    int r16 = lane & 15, kh = lane >> 4;
    int mb = wm * 64;

    const unsigned short* eh0 = ETh + ((size_t)n * TPAD + tb + r16) * KK + kh * 8;
    const unsigned short* vh0 = Vth + ((size_t)n * MM + mb + r16) * KK + kh * 8;
    const unsigned short* vl0 = Vtl + ((size_t)n * MM + mb + r16) * KK + kh * 8;

    f32x4 acc[2][4];
#pragma unroll
    for (int tt = 0; tt < 2; ++tt)
#pragma unroll
        for (int mm = 0; mm < 4; ++mm) acc[tt][mm] = (f32x4){0.f, 0.f, 0.f, 0.f};

#pragma unroll
    for (int kb = 0; kb < 8; ++kb) {
        int ko = kb * 32;
        bf16x8 ah0 = *(const bf16x8*)(eh0 + ko);
        bf16x8 ah1 = *(const bf16x8*)(eh0 + 16 * KK + ko);
#pragma unroll
        for (int mm = 0; mm < 4; ++mm) {
            bf16x8 bh = *(const bf16x8*)(vh0 + (size_t)mm * 16 * KK + ko);
            bf16x8 bl = *(const bf16x8*)(vl0 + (size_t)mm * 16 * KK + ko);
            acc[0][mm] = __builtin_amdgcn_mfma_f32_16x16x32_bf16(ah0, bh, acc[0][mm], 0, 0, 0);
            acc[0][mm] = __builtin_amdgcn_mfma_f32_16x16x32_bf16(ah0, bl, acc[0][mm], 0, 0, 0);
            acc[1][mm] = __builtin_amdgcn_mfma_f32_16x16x32_bf16(ah1, bh, acc[1][mm], 0, 0, 0);
            acc[1][mm] = __builtin_amdgcn_mfma_f32_16x16x32_bf16(ah1, bl, acc[1][mm], 0, 0, 0);
        }
    }

#pragma unroll
    for (int tt = 0; tt < 2; ++tt) {
#pragma unroll
        for (int r = 0; r < 4; ++r) {
            int t = tb + tt * 16 + kh * 4 + r;
            if (t < TT) {
                float c0 = wcg[(size_t)(n * TT + t) * 2];
                float c1 = wcg[(size_t)(n * TT + t) * 2 + 1];
#pragma unroll
                for (int mm = 0; mm < 4; ++mm) {
                    int m = mb + mm * 16 + r16;
                    float pw0 = projw[m], pw1 = projw[MM + m];
                    out[((size_t)n * TT + t) * MM + m] =
                        acc[tt][mm][r] + c0 * pw0 + c1 * pw1;
                }
            }
        }
    }
}

// ---------------- K3b (fallback): s_load E rows + coalesced V (R7) -----------
__global__ __launch_bounds__(384) void k_out(
    const float* __restrict__ V, const float* __restrict__ projw,
    const float* __restrict__ wcg, const float* __restrict__ ET,
    float* __restrict__ out) {
    int tid = threadIdx.x;
    int tb = blockIdx.x * TOB;
    int n = blockIdx.y;
    int nK = n * KK;
    const float* Vn = V + (size_t)n * KK * MM;
    const float* Eb = ET + (size_t)nK * TP + tb;
    int m = tid;

    float acc[TOB];
#pragma unroll
    for (int t = 0; t < TOB; ++t) acc[t] = 0.f;

    for (int kx = 0; kx < KK; ++kx) {
        const float4* ep = (const float4*)(Eb + (size_t)kx * TP);  // uniform -> s_load
        float vv = Vn[(size_t)kx * MM + m];
#pragma unroll
        for (int q = 0; q < TOB / 4; ++q) {
            float4 e = ep[q];
            acc[4 * q + 0] = fmaf(e.x, vv, acc[4 * q + 0]);
            acc[4 * q + 1] = fmaf(e.y, vv, acc[4 * q + 1]);
            acc[4 * q + 2] = fmaf(e.z, vv, acc[4 * q + 2]);
            acc[4 * q + 3] = fmaf(e.w, vv, acc[4 * q + 3]);
        }
    }

    float pw0 = projw[m], pw1 = projw[MM + m];
#pragma unroll
    for (int t = 0; t < TOB; ++t) {
        int tt = tb + t;
        if (tt < TT) {
            float c0 = wcg[(size_t)(n * TT + tt) * 2];
            float c1 = wcg[(size_t)(n * TT + tt) * 2 + 1];
            out[((size_t)n * TT + tt) * MM + m] = acc[t] + c0 * pw0 + c1 * pw1;
        }
    }
}

extern "C" void kernel_launch(void* const* d_in, const int* in_sizes, int n_in,
                              void* d_out, int out_size, void* d_ws, size_t ws_size,
                              hipStream_t stream) {
    const float* V   = (const float*)d_in[0];
    const float* dur = (const float*)d_in[1];
    const float* cw  = (const float*)d_in[2];
    const float* cb  = (const float*)d_in[3];
    const float* bng = (const float*)d_in[4];
    const float* bnb = (const float*)d_in[5];
    const float* bnm = (const float*)d_in[6];
    const float* bnv = (const float*)d_in[7];
    const float* w1  = (const float*)d_in[8];
    const float* b1  = (const float*)d_in[9];
    const float* w2  = (const float*)d_in[10];
    const float* b2  = (const float*)d_in[11];
    const float* w3  = (const float*)d_in[12];
    const float* b3  = (const float*)d_in[13];
    const float* aw1 = (const float*)d_in[14];
    const float* ab1 = (const float*)d_in[15];
    const float* aw2 = (const float*)d_in[16];
    const float* ab2 = (const float*)d_in[17];
    const float* pw  = (const float*)d_in[18];
    float* out = (float*)d_out;
    float* ws = (float*)d_ws;

    float* wsS  = ws;                 // 4096 floats
    float* wsQ1 = ws + 8192;          // 65536
    float* wsQA = ws + 73728;         // 8192
    float* wcg  = ws + 81920;         // 32768
    char*  base = (char*)(ws + 114688);

    size_t sz_ETh = (size_t)NN * TPAD * KK * 2;   // 8,388,608
    size_t sz_Vt  = (size_t)NN * MM * KK * 2;     // 3,145,728
    size_t need   = 114688 * 4 + 2 * sz_ETh + 2 * sz_Vt;   // same layout as R14
    bool mfma_path = (ws_size >= need);

    if (mfma_path) {
        unsigned short* ETh = (unsigned short*)base;
        unsigned short* Vth = (unsigned short*)(base + 2 * sz_ETh);
        unsigned short* Vtl = (unsigned short*)(base + 2 * sz_ETh + sz_Vt);
        int nvt = 6 * 4 * NN;   // 384
        hipLaunchKernelGGL(k_init, dim3(16 + nvt + 64 * NN), dim3(256), 0, stream,
                           dur, wsS, V, Vth, Vtl, cw, cb, bng, bnb, bnm, bnv,
                           w1, b1, aw1, ab1, wsQ1, wsQA, nvt);
        hipLaunchKernelGGL(k_score, dim3(TT / TCH, NN), dim3(256), 0,
                           stream, w1, w2, b2, w3, b3, aw1, aw2, ab2, wsS, wsQ1,
                           wsQA, wcg, (float*)nullptr, ETh, 1);
        hipLaunchKernelGGL(k_gemm, dim3(TPAD / 64, NN), dim3(768), 0, stream,
                           ETh, Vth, Vtl, wcg, pw, out);
    } else {
        float* ETf = (float*)base;
        hipLaunchKernelGGL(k_init, dim3(16 + 64 * NN), dim3(256), 0, stream,
                           dur, wsS, V, (unsigned short*)nullptr,
                           (unsigned short*)nullptr, cw, cb, bng, bnb, bnm, bnv,
                           w1, b1, aw1, ab1, wsQ1, wsQA, 0);
        hipLaunchKernelGGL(k_score, dim3(TT / TCH, NN), dim3(256), 0,
                           stream, w1, w2, b2, w3, b3, aw1, aw2, ab2, wsS, wsQ1,
                           wsQA, wcg, ETf, (unsigned short*)nullptr, 0);
        hipLaunchKernelGGL(k_out, dim3((TT + TOB - 1) / TOB, NN), dim3(384), 0,
                           stream, V, pw, wcg, ETf, out);
    }
}

// Round 19
// 123.372 us; speedup vs baseline: 1.0474x; 1.0004x over previous
//
#include <hip/hip_runtime.h>

#define NN 16
#define KK 256
#define TT 1000
#define MM 384
#define TCH 8      // t's per k_score block (125 blocks exactly, no tail)
#define TOB 28     // t's per k_out block (fallback path)
#define TP 1008    // padded T stride for fallback fp32 E_T
#define TPAD 1024  // padded T rows for bf16 ET (MFMA path)

typedef short bf16x8 __attribute__((ext_vector_type(8)));
typedef float f32x4 __attribute__((ext_vector_type(4)));

__device__ __forceinline__ float fast_rcp(float x) { return __builtin_amdgcn_rcpf(x); }
__device__ __forceinline__ float silu_f(float x) {
    float e = __expf(-x);
    return x * fast_rcp(1.0f + e);
}
__device__ __forceinline__ unsigned short f2bf_rne(float f) {
    unsigned u = __float_as_uint(f);
    unsigned r = u + 0x7fff + ((u >> 16) & 1);
    return (unsigned short)(r >> 16);
}
__device__ __forceinline__ float bf2f(unsigned short h) {
    return __uint_as_float((unsigned)h << 16);
}

// ---- K1 fat: scan (16) + V^T bf16 (nvt) + conv (256 blocks x 16 k each) ----
// conv computes d=relu(exp(dur)-1) locally -> no dependency on scan output.
// conv block owns 16 k's: weights loaded to LDS ONCE, 4 outer iterations.
__global__ __launch_bounds__(256) void k_init(
    const float* __restrict__ dur_out, float* __restrict__ wsS,
    const float* __restrict__ V,
    unsigned short* __restrict__ Vth, unsigned short* __restrict__ Vtl,
    const float* __restrict__ conv_w, const float* __restrict__ conv_b,
    const float* __restrict__ bn_g, const float* __restrict__ bn_b,
    const float* __restrict__ bn_m, const float* __restrict__ bn_v,
    const float* __restrict__ w1, const float* __restrict__ b1,
    const float* __restrict__ aw1, const float* __restrict__ ab1,
    float* __restrict__ wsQ1, float* __restrict__ wsQA, int nvt) {
    __shared__ float shmem[8 * 3 * MM];   // 36 KB union: scan(1KB)/tile(16.3KB)/wt
    int tid = threadIdx.x;
    int bid = blockIdx.x;

    if (bid < 16) {
        // ---- scan ----
        float* lds = shmem;
        int n = bid, k = tid;
        float d = __expf(dur_out[n * KK + k]) - 1.0f;
        d = fmaxf(d, 0.0f);
        lds[k] = d;
        __syncthreads();
        float run = d;
        for (int off = 1; off < KK; off <<= 1) {
            float v = (k >= off) ? lds[k - off] : 0.0f;
            __syncthreads();
            run += v;
            lds[k] = run;
            __syncthreads();
        }
        wsS[n * KK + k] = run - d;
    } else if (bid < 16 + nvt) {
        // ---- V -> V^T bf16 hi/lo ----
        float (*tile)[65] = (float(*)[65])shmem;
        int id = bid - 16;
        int m0 = (id % 6) * 64;
        int k0 = ((id / 6) & 3) * 64;
        int n = id / 24;
        const float* Vn = V + (size_t)n * KK * MM;
        int mo = tid & 63, ks = tid >> 6;
        for (int kk = ks; kk < 64; kk += 4)
            tile[kk][mo] = Vn[(size_t)(k0 + kk) * MM + m0 + mo];
        __syncthreads();
        int ko = tid & 63, ms = tid >> 6;
        for (int mm = ms; mm < 64; mm += 4) {
            float v = tile[ko][mm];
            unsigned short hi = f2bf_rne(v);
            unsigned short lo = f2bf_rne(v - bf2f(hi));
            size_t o = ((size_t)n * MM + m0 + mm) * KK + k0 + ko;
            Vth[o] = hi;
            Vtl[o] = lo;
        }
    } else {
        // ---- conv1d(3,same)+BN+silu -> fold into q1/qA; 16 k per block ----
        float* wt = shmem;   // [c][tap][m]
        int id = bid - 16 - nvt;
        int kcb = id & 15;   // 16 chunks of 16 k
        int n = id >> 4;
        for (int i = tid; i < 3 * MM * 8; i += 256) {
            int tap = i / (MM * 8);
            int r = i - tap * (MM * 8);
            int m = r >> 3, c = r & 7;
            wt[(c * 3 + tap) * MM + m] = conv_w[i];
        }
        __syncthreads();

        int wv = tid >> 6, lane = tid & 63;
        const float* Vn = V + (size_t)n * KK * MM;

        for (int it = 0; it < 4; ++it) {
            int k = kcb * 16 + it * 4 + wv;

            float p[8];
#pragma unroll
            for (int c = 0; c < 8; ++c) p[c] = 0.f;

#pragma unroll
            for (int tap = 0; tap < 3; ++tap) {
                int kk = k + tap - 1;
                if (kk < 0 || kk >= KK) continue;   // wave-uniform branch
                const float* vrow = Vn + (size_t)kk * MM;
#pragma unroll
                for (int j = 0; j < 6; ++j) {
                    int m = lane + 64 * j;
                    float v = vrow[m];              // coalesced
#pragma unroll
                    for (int c = 0; c < 8; ++c)
                        p[c] = fmaf(v, wt[(c * 3 + tap) * MM + m], p[c]);
                }
            }
#pragma unroll
            for (int c = 0; c < 8; ++c) {
#pragma unroll
                for (int off = 32; off >= 1; off >>= 1) p[c] += __shfl_xor(p[c], off);
            }
            float cv[8];
#pragma unroll
            for (int c = 0; c < 8; ++c) {
                float xx = p[c] + conv_b[c];
                float bn = (xx - bn_m[c]) * (bn_g[c] * rsqrtf(bn_v[c] + 1e-3f)) + bn_b[c];
                cv[c] = silu_f(bn);
            }
            float d = fmaxf(__expf(dur_out[n * KK + k]) - 1.0f, 0.0f);
            if (lane < 16) {
                int j = lane;
                float q = fmaf(d, w1[16 + j], b1[j]);
#pragma unroll
                for (int c = 0; c < 8; ++c) q = fmaf(cv[c], w1[(2 + c) * 16 + j], q);
                wsQ1[((size_t)(n * KK + k)) * 16 + j] = q;
            } else if (lane < 18) {
                int pp = lane - 16;
                float q = fmaf(d, aw1[2 + pp], ab1[pp]);
#pragma unroll
                for (int c = 0; c < 8; ++c) q = fmaf(cv[c], aw1[(2 + c) * 2 + pp], q);
                wsQA[(size_t)(n * KK + k) * 2 + pp] = q;
            }
        }
    }
}

// ---------------- K3a: scores -> softmax -> E (bf16 or fp32) + aux C ---------
// Phase A: t-quad with exp-chaining; w2/w3 via uniform scalar loads; fp32 FMA
// (f16 dot2 REJECTED: h scales with t-S, f16 rel-err 2^-11 -> softmax breaks).
// NO min-waves launch bound (caps spill -- R3/R4 lesson).
__global__ __launch_bounds__(256) void k_score(
    const float* __restrict__ w1, const float* __restrict__ w2g,
    const float* __restrict__ b2g, const float* __restrict__ w3g,
    const float* __restrict__ b3g, const float* __restrict__ aw1,
    const float* __restrict__ aw2g, const float* __restrict__ ab2g,
    const float* __restrict__ wsS, const float* __restrict__ wsQ1,
    const float* __restrict__ wsQA, float* __restrict__ wcg,
    float* __restrict__ ETf, unsigned short* __restrict__ ETh,
    int use_bf16) {
    __shared__ __align__(16) float sc[TCH * KK];   // 8 KB
    __shared__ __align__(16) float rl[16];

    int tid = threadIdx.x;
    int tb = blockIdx.x * TCH;
    int n = blockIdx.y;
    int nK = n * KK;

    if (tid < 16) rl[tid] = w1[tid] - w1[16 + tid];

    float b3v = b3g[0];
    float b2r[16];
    {
        const float4* bp = (const float4*)b2g;
#pragma unroll
        for (int g = 0; g < 4; ++g) {
            float4 b = bp[g];
            b2r[4 * g + 0] = b.x; b2r[4 * g + 1] = b.y;
            b2r[4 * g + 2] = b.z; b2r[4 * g + 3] = b.w;
        }
    }
    int k = tid;
    float S_k = wsS[nK + k];
    float q1[16];
    {
        const float4* q1p = (const float4*)&wsQ1[(size_t)(nK + k) * 16];
#pragma unroll
        for (int g = 0; g < 4; ++g) {
            float4 qv = q1p[g];
            q1[4 * g + 0] = qv.x; q1[4 * g + 1] = qv.y;
            q1[4 * g + 2] = qv.z; q1[4 * g + 3] = qv.w;
        }
    }
    __syncthreads();

    float er[16];
#pragma unroll
    for (int j = 0; j < 16; ++j) er[j] = __expf(-rl[j]);

    // ---- phase A: scores, 4 t's at a time; acc pre-seeded with b2 ----
    for (int tq = 0; tq < TCH / 4; ++tq) {
        float s0 = (float)(tb + 4 * tq + 1) - S_k;
        float aA[16], aB[16], aC[16], aD[16];
#pragma unroll
        for (int j = 0; j < 16; ++j) {
            aA[j] = b2r[j]; aB[j] = b2r[j]; aC[j] = b2r[j]; aD[j] = b2r[j];
        }
#pragma unroll
        for (int j1 = 0; j1 < 16; ++j1) {
            float r = rl[j1];
            float q = q1[j1];
            float uA = fmaf(s0, r, q);
            float uB = uA + r;
            float uC = uB + r;
            float uD = uC + r;
            float ej = er[j1];
            float eA = __expf(-uA);
            float eB = eA * ej;
            float eC = eB * ej;
            float eD = eC * ej;
            float hA = uA * fast_rcp(1.0f + eA);
            float hB = uB * fast_rcp(1.0f + eB);
            float hC = uC * fast_rcp(1.0f + eC);
            float hD = uD * fast_rcp(1.0f + eD);
            const float4* wr = (const float4*)&w2g[j1 * 16];   // uniform -> s_load
#pragma unroll
            for (int g = 0; g < 4; ++g) {
                float4 w = wr[g];
                aA[4 * g + 0] = fmaf(hA, w.x, aA[4 * g + 0]);
                aA[4 * g + 1] = fmaf(hA, w.y, aA[4 * g + 1]);
                aA[4 * g + 2] = fmaf(hA, w.z, aA[4 * g + 2]);
                aA[4 * g + 3] = fmaf(hA, w.w, aA[4 * g + 3]);
                aB[4 * g + 0] = fmaf(hB, w.x, aB[4 * g + 0]);
                aB[4 * g + 1] = fmaf(hB, w.y, aB[4 * g + 1]);
                aB[4 * g + 2] = fmaf(hB, w.z, aB[4 * g + 2]);
                aB[4 * g + 3] = fmaf(hB, w.w, aB[4 * g + 3]);
                aC[4 * g + 0] = fmaf(hC, w.x, aC[4 * g + 0]);
                aC[4 * g + 1] = fmaf(hC, w.y, aC[4 * g + 1]);
                aC[4 * g + 2] = fmaf(hC, w.z, aC[4 * g + 2]);
                aC[4 * g + 3] = fmaf(hC, w.w, aC[4 * g + 3]);
                aD[4 * g + 0] = fmaf(hD, w.x, aD[4 * g + 0]);
                aD[4 * g + 1] = fmaf(hD, w.y, aD[4 * g + 1]);
                aD[4 * g + 2] = fmaf(hD, w.z, aD[4 * g + 2]);
                aD[4 * g + 3] = fmaf(hD, w.w, aD[4 * g + 3]);
            }
        }
        float scA = b3v, scB = b3v, scC = b3v, scD = b3v;
#pragma unroll
        for (int g = 0; g < 4; ++g) {
            float4 wq = *(const float4*)&w3g[4 * g];   // uniform -> s_load
            scA = fmaf(silu_f(aA[4 * g + 0]), wq.x, scA);
            scA = fmaf(silu_f(aA[4 * g + 1]), wq.y, scA);
            scA = fmaf(silu_f(aA[4 * g + 2]), wq.z, scA);
            scA = fmaf(silu_f(aA[4 * g + 3]), wq.w, scA);
            scB = fmaf(silu_f(aB[4 * g + 0]), wq.x, scB);
            scB = fmaf(silu_f(aB[4 * g + 1]), wq.y, scB);
            scB = fmaf(silu_f(aB[4 * g + 2]), wq.z, scB);
            scB = fmaf(silu_f(aB[4 * g + 3]), wq.w, scB);
            scC = fmaf(silu_f(aC[4 * g + 0]), wq.x, scC);
            scC = fmaf(silu_f(aC[4 * g + 1]), wq.y, scC);
            scC = fmaf(silu_f(aC[4 * g + 2]), wq.z, scC);
            scC = fmaf(silu_f(aC[4 * g + 3]), wq.w, scC);
            scD = fmaf(silu_f(aD[4 * g + 0]), wq.x, scD);
            scD = fmaf(silu_f(aD[4 * g + 1]), wq.y, scD);
            scD = fmaf(silu_f(aD[4 * g + 2]), wq.z, scD);
            scD = fmaf(silu_f(aD[4 * g + 3]), wq.w, scD);
        }
        sc[(4 * tq + 0) * KK + k] = scA;
        sc[(4 * tq + 1) * KK + k] = scB;
        sc[(4 * tq + 2) * KK + k] = scC;
        sc[(4 * tq + 3) * KK + k] = scD;
    }
    __syncthreads();

    // ---- softmax over k (wave-parallel) + aux C; normalize in place ----
    {
        float rA0 = aw1[0] - aw1[2];
        float rA1 = aw1[1] - aw1[3];
        float aw200 = aw2g[0], aw201 = aw2g[1], aw210 = aw2g[2], aw211 = aw2g[3];
        float ab20 = ab2g[0], ab21 = ab2g[1];
        int wv = tid >> 6, lane = tid & 63;
        float S4[4]; float2 QA4[4];
#pragma unroll
        for (int j = 0; j < 4; ++j) {
            int kk2 = lane + 64 * j;
            S4[j] = wsS[nK + kk2];
            QA4[j] = *(const float2*)&wsQA[(size_t)(nK + kk2) * 2];
        }
#pragma unroll
        for (int i = 0; i < 2; ++i) {
            int t = wv * 2 + i;
            int tt = tb + t;
            float v0 = sc[t * KK + lane];
            float v1 = sc[t * KK + lane + 64];
            float v2 = sc[t * KK + lane + 128];
            float v3 = sc[t * KK + lane + 192];
            float mx = fmaxf(fmaxf(v0, v1), fmaxf(v2, v3));
#pragma unroll
            for (int off = 32; off >= 1; off >>= 1) mx = fmaxf(mx, __shfl_xor(mx, off));
            float e0 = __expf(v0 - mx), e1 = __expf(v1 - mx);
            float e2 = __expf(v2 - mx), e3 = __expf(v3 - mx);
            float ssum = e0 + e1 + e2 + e3;
            float wc0 = 0.f, wc1 = 0.f;
            float tc = (float)(tt + 1);
            float ear[4] = {e0, e1, e2, e3};
#pragma unroll
            for (int j = 0; j < 4; ++j) {
                float s = tc - S4[j];
                float a0 = silu_f(fmaf(s, rA0, QA4[j].x));
                float a1 = silu_f(fmaf(s, rA1, QA4[j].y));
                float c0 = silu_f(fmaf(a1, aw210, fmaf(a0, aw200, ab20)));
                float c1 = silu_f(fmaf(a1, aw211, fmaf(a0, aw201, ab21)));
                wc0 = fmaf(ear[j], c0, wc0);
                wc1 = fmaf(ear[j], c1, wc1);
            }
#pragma unroll
            for (int off = 32; off >= 1; off >>= 1) {
                ssum += __shfl_xor(ssum, off);
                wc0 += __shfl_xor(wc0, off);
                wc1 += __shfl_xor(wc1, off);
            }
            float inv = fast_rcp(ssum);
            sc[t * KK + lane]       = e0 * inv;
            sc[t * KK + lane + 64]  = e1 * inv;
            sc[t * KK + lane + 128] = e2 * inv;
            sc[t * KK + lane + 192] = e3 * inv;
            if (lane == 0) {
                wcg[(size_t)(n * TT + tt) * 2]     = wc0 * inv;
                wcg[(size_t)(n * TT + tt) * 2 + 1] = wc1 * inv;
            }
        }
    }
    __syncthreads();

    if (use_bf16) {
        // E as bf16 hi only (E in [0,1]; El dropped -- R16-proven)
#pragma unroll
        for (int t2 = 0; t2 < TCH; ++t2) {
            float e = sc[t2 * KK + k];
            size_t o = ((size_t)n * TPAD + tb + t2) * KK + k;
            ETh[o] = f2bf_rne(e);
        }
    } else {
        for (int idx = tid; idx < TCH * KK; idx += 256) {
            int k2 = idx >> 3, t2 = idx & 7;
            ETf[((size_t)(nK + k2)) * TP + tb + t2] = sc[t2 * KK + k2];
        }
    }
}

// ---------------- K3b (MFMA): O = E @ V + aux, 64t per block, 2-term ---------
// 768 thr = 12 waves = 2 t-subtiles(32t) x 6 m-tiles(64m). Per (kb,mm,tt):
// EhVh + EhVl. fp32 accumulate. (R16-proven)
__global__ __launch_bounds__(768) void k_gemm(
    const unsigned short* __restrict__ ETh,
    const unsigned short* __restrict__ Vth, const unsigned short* __restrict__ Vtl,
    const float* __restrict__ wcg, const float* __restrict__ projw,
    float* __restrict__ out) {
    int tid = threadIdx.x;
    int w = tid >> 6, lane = tid & 63;
    int ts = (w >= 6) ? 1 : 0;          // t-subtile within block
    int wm = (w >= 6) ? (w - 6) : w;    // m-tile index 0..5
    int tb = blockIdx.x * 64 + ts * 32;
    int n = blockIdx.y;
    int r16 = lane & 15, kh = lane >> 4;
    int mb = wm * 64;

    const unsigned short* eh0 = ETh + ((size_t)n * TPAD + tb + r16) * KK + kh * 8;
    const unsigned short* vh0 = Vth + ((size_t)n * MM + mb + r16) * KK + kh * 8;
    const unsigned short* vl0 = Vtl + ((size_t)n * MM + mb + r16) * KK + kh * 8;

    f32x4 acc[2][4];
#pragma unroll
    for (int tt = 0; tt < 2; ++tt)
#pragma unroll
        for (int mm = 0; mm < 4; ++mm) acc[tt][mm] = (f32x4){0.f, 0.f, 0.f, 0.f};

#pragma unroll
    for (int kb = 0; kb < 8; ++kb) {
        int ko = kb * 32;
        bf16x8 ah0 = *(const bf16x8*)(eh0 + ko);
        bf16x8 ah1 = *(const bf16x8*)(eh0 + 16 * KK + ko);
#pragma unroll
        for (int mm = 0; mm < 4; ++mm) {
            bf16x8 bh = *(const bf16x8*)(vh0 + (size_t)mm * 16 * KK + ko);
            bf16x8 bl = *(const bf16x8*)(vl0 + (size_t)mm * 16 * KK + ko);
            acc[0][mm] = __builtin_amdgcn_mfma_f32_16x16x32_bf16(ah0, bh, acc[0][mm], 0, 0, 0);
            acc[0][mm] = __builtin_amdgcn_mfma_f32_16x16x32_bf16(ah0, bl, acc[0][mm], 0, 0, 0);
            acc[1][mm] = __builtin_amdgcn_mfma_f32_16x16x32_bf16(ah1, bh, acc[1][mm], 0, 0, 0);
            acc[1][mm] = __builtin_amdgcn_mfma_f32_16x16x32_bf16(ah1, bl, acc[1][mm], 0, 0, 0);
        }
    }

#pragma unroll
    for (int tt = 0; tt < 2; ++tt) {
#pragma unroll
        for (int r = 0; r < 4; ++r) {
            int t = tb + tt * 16 + kh * 4 + r;
            if (t < TT) {
                float c0 = wcg[(size_t)(n * TT + t) * 2];
                float c1 = wcg[(size_t)(n * TT + t) * 2 + 1];
#pragma unroll
                for (int mm = 0; mm < 4; ++mm) {
                    int m = mb + mm * 16 + r16;
                    float pw0 = projw[m], pw1 = projw[MM + m];
                    out[((size_t)n * TT + t) * MM + m] =
                        acc[tt][mm][r] + c0 * pw0 + c1 * pw1;
                }
            }
        }
    }
}

// ---------------- K3b (fallback): s_load E rows + coalesced V (R7) -----------
__global__ __launch_bounds__(384) void k_out(
    const float* __restrict__ V, const float* __restrict__ projw,
    const float* __restrict__ wcg, const float* __restrict__ ET,
    float* __restrict__ out) {
    int tid = threadIdx.x;
    int tb = blockIdx.x * TOB;
    int n = blockIdx.y;
    int nK = n * KK;
    const float* Vn = V + (size_t)n * KK * MM;
    const float* Eb = ET + (size_t)nK * TP + tb;
    int m = tid;

    float acc[TOB];
#pragma unroll
    for (int t = 0; t < TOB; ++t) acc[t] = 0.f;

    for (int kx = 0; kx < KK; ++kx) {
        const float4* ep = (const float4*)(Eb + (size_t)kx * TP);  // uniform -> s_load
        float vv = Vn[(size_t)kx * MM + m];
#pragma unroll
        for (int q = 0; q < TOB / 4; ++q) {
            float4 e = ep[q];
            acc[4 * q + 0] = fmaf(e.x, vv, acc[4 * q + 0]);
            acc[4 * q + 1] = fmaf(e.y, vv, acc[4 * q + 1]);
            acc[4 * q + 2] = fmaf(e.z, vv, acc[4 * q + 2]);
            acc[4 * q + 3] = fmaf(e.w, vv, acc[4 * q + 3]);
        }
    }

    float pw0 = projw[m], pw1 = projw[MM + m];
#pragma unroll
    for (int t = 0; t < TOB; ++t) {
        int tt = tb + t;
        if (tt < TT) {
            float c0 = wcg[(size_t)(n * TT + tt) * 2];
            float c1 = wcg[(size_t)(n * TT + tt) * 2 + 1];
            out[((size_t)n * TT + tt) * MM + m] = acc[t] + c0 * pw0 + c1 * pw1;
        }
    }
}

extern "C" void kernel_launch(void* const* d_in, const int* in_sizes, int n_in,
                              void* d_out, int out_size, void* d_ws, size_t ws_size,
                              hipStream_t stream) {
    const float* V   = (const float*)d_in[0];
    const float* dur = (const float*)d_in[1];
    const float* cw  = (const float*)d_in[2];
    const float* cb  = (const float*)d_in[3];
    const float* bng = (const float*)d_in[4];
    const float* bnb = (const float*)d_in[5];
    const float* bnm = (const float*)d_in[6];
    const float* bnv = (const float*)d_in[7];
    const float* w1  = (const float*)d_in[8];
    const float* b1  = (const float*)d_in[9];
    const float* w2  = (const float*)d_in[10];
    const float* b2  = (const float*)d_in[11];
    const float* w3  = (const float*)d_in[12];
    const float* b3  = (const float*)d_in[13];
    const float* aw1 = (const float*)d_in[14];
    const float* ab1 = (const float*)d_in[15];
    const float* aw2 = (const float*)d_in[16];
    const float* ab2 = (const float*)d_in[17];
    const float* pw  = (const float*)d_in[18];
    float* out = (float*)d_out;
    float* ws = (float*)d_ws;

    float* wsS  = ws;                 // 4096 floats
    float* wsQ1 = ws + 8192;          // 65536
    float* wsQA = ws + 73728;         // 8192
    float* wcg  = ws + 81920;         // 32768
    char*  base = (char*)(ws + 114688);

    size_t sz_ETh = (size_t)NN * TPAD * KK * 2;   // 8,388,608
    size_t sz_Vt  = (size_t)NN * MM * KK * 2;     // 3,145,728
    size_t need   = 114688 * 4 + 2 * sz_ETh + 2 * sz_Vt;   // same layout as R14
    bool mfma_path = (ws_size >= need);

    if (mfma_path) {
        unsigned short* ETh = (unsigned short*)base;
        unsigned short* Vth = (unsigned short*)(base + 2 * sz_ETh);
        unsigned short* Vtl = (unsigned short*)(base + 2 * sz_ETh + sz_Vt);
        int nvt = 6 * 4 * NN;   // 384
        hipLaunchKernelGGL(k_init, dim3(16 + nvt + 16 * NN), dim3(256), 0, stream,
                           dur, wsS, V, Vth, Vtl, cw, cb, bng, bnb, bnm, bnv,
                           w1, b1, aw1, ab1, wsQ1, wsQA, nvt);
        hipLaunchKernelGGL(k_score, dim3(TT / TCH, NN), dim3(256), 0,
                           stream, w1, w2, b2, w3, b3, aw1, aw2, ab2, wsS, wsQ1,
                           wsQA, wcg, (float*)nullptr, ETh, 1);
        hipLaunchKernelGGL(k_gemm, dim3(TPAD / 64, NN), dim3(768), 0, stream,
                           ETh, Vth, Vtl, wcg, pw, out);
    } else {
        float* ETf = (float*)base;
        hipLaunchKernelGGL(k_init, dim3(16 + 16 * NN), dim3(256), 0, stream,
                           dur, wsS, V, (unsigned short*)nullptr,
                           (unsigned short*)nullptr, cw, cb, bng, bnb, bnm, bnv,
                           w1, b1, aw1, ab1, wsQ1, wsQA, 0);
        hipLaunchKernelGGL(k_score, dim3(TT / TCH, NN), dim3(256), 0,
                           stream, w1, w2, b2, w3, b3, aw1, aw2, ab2, wsS, wsQ1,
                           wsQA, wcg, ETf, (unsigned short*)nullptr, 0);
        hipLaunchKernelGGL(k_out, dim3((TT + TOB - 1) / TOB, NN), dim3(384), 0,
                           stream, V, pw, wcg, ETf, out);
    }
}